// Round 3
// baseline (7769.213 us; speedup 1.0000x reference)
//
#include <hip/hip_runtime.h>
#include <cstdint>
#include <cstddef>

// ---------------------------------------------------------------------------
// Register-resident persistent-RNN decoder: 2-layer LSTM (H=1024) + Luong dot
// attention, T=256 sequential steps. 256 blocks x 512 threads (8 waves), ONE
// block per CU (__launch_bounds__(512,1) -> <=256 VGPR -> co-residency
// guaranteed). ALL weights live in registers for the whole kernel:
//   per wave: 4 LSTM rows layer0 (64 f) + 4 rows layer1 (64 f) +
//             1 attention row (16 f) + 1 MT row (16 f, waves 4-7).
// Cross-block communication: NO grid barriers. Every shared float is an 8-byte
// (tag,value) atomic slot in ws; readiness and data arrive atomically in one
// MALL message. One stager wave per vector polls the 1024 slots, writes LDS,
// sets an LDS generation flag; other waves spin on the flag (intra-CU, cheap).
// Main loop contains ZERO __syncthreads.
//
// Roles per block (dims j0=4b..j0+3; A/B pair: owner w=2d computes gates i,f;
// partner w=2d+1 computes g,o; combine via LDS flag):
//   w0..w5: LSTM pair work; C: w<4 -> score enc[j0+w]*h1', w>=4 -> y2 row
//   w4..w7: phase D (softmax over staged scores + reg-MT dot + tanh), dim w-4
//   w6 stages: x (A), h0' (B), h1' (C);  w7 stages: h0_old (A), h1_old (B),
//              scores (D)
// Slot safety: x/scores single-buffered (overwrite gated through the step's
// dependency chain), h0/h1 parity double-buffered. Poison 0xAA = negative tag.
// ---------------------------------------------------------------------------

#define TSTEPS 256
#define HDIM   1024
#define NBLK   256
#define NTHR   512

typedef unsigned long long u64;

// ws layout in u64 units
#define WX   0                 // x feedback [1024]
#define WH0  1024              // h0 parity [2][1024]
#define WH1  3072              // h1 parity [2][1024]
#define WSC  5120              // scores [1024]
#define WMT  6144              // MT f32[1024*1024] starts here

__device__ __forceinline__ float wred_sum(float v) {
#pragma unroll
  for (int m = 32; m >= 1; m >>= 1) v += __shfl_xor(v, m, 64);
  return v;
}
__device__ __forceinline__ float wred_max(float v) {
#pragma unroll
  for (int m = 32; m >= 1; m >>= 1) v = fmaxf(v, __shfl_xor(v, m, 64));
  return v;
}
__device__ __forceinline__ void astore64(u64* p, int tag, float v) {
  u64 x = ((u64)(unsigned)tag << 32) | (u64)(unsigned)__float_as_uint(v);
  __hip_atomic_store(p, x, __ATOMIC_RELAXED, __HIP_MEMORY_SCOPE_AGENT);
}
__device__ __forceinline__ u64 aload64(const u64* p) {
  return __hip_atomic_load(p, __ATOMIC_RELAXED, __HIP_MEMORY_SCOPE_AGENT);
}
__device__ __forceinline__ void lds_set(int* f, int v) {
  __hip_atomic_store(f, v, __ATOMIC_RELEASE, __HIP_MEMORY_SCOPE_WORKGROUP);
}
__device__ __forceinline__ void lds_wait(int* f, int v) {
  while (__hip_atomic_load(f, __ATOMIC_ACQUIRE, __HIP_MEMORY_SCOPE_WORKGROUP) < v) {}
}
__device__ __forceinline__ float sigf(float x) { return 1.f / (1.f + __expf(-x)); }

// poll 1024 tagged slots (16 per lane, stride 64), deposit values to LDS, flag
__device__ __forceinline__ void stage_poll(const u64* slots, int tag, float* buf,
                                           int* flag, int fval, int l) {
  float v[16];
  unsigned miss = 0xffffu;
  while (miss) {
#pragma unroll
    for (int i = 0; i < 16; ++i) {
      if (miss & (1u << i)) {
        u64 x = aload64(slots + l + 64 * i);
        if ((int)(x >> 32) == tag) { v[i] = __uint_as_float((unsigned)x); miss &= ~(1u << i); }
      }
    }
    if (miss == 0xffffu) __builtin_amdgcn_s_sleep(8);
    else if (miss)       __builtin_amdgcn_s_sleep(1);
  }
#pragma unroll
  for (int i = 0; i < 16; ++i) buf[l + 64 * i] = v[i];
  lds_set(flag, fval);
}
__device__ __forceinline__ void stage_direct(const float* src, float* buf,
                                             int* flag, int fval, int l) {
#pragma unroll
  for (int i = 0; i < 16; ++i) buf[l + 64 * i] = src[l + 64 * i];
  lds_set(flag, fval);
}

__global__ void __launch_bounds__(NTHR, 1) decoder_persist(
    const float* __restrict__ enc,   // [1024,1024]
    const float* __restrict__ hid,   // [2,1024]
    const float* __restrict__ cell,  // [2,1024]
    const float* __restrict__ w_ih,  // [2,4096,1024]
    const float* __restrict__ w_hh,  // [2,4096,1024]
    const float* __restrict__ b_ih,  // [2,4096]
    const float* __restrict__ b_hh,  // [2,4096]
    const float* __restrict__ wcat,  // [1024,2048]
    const float* __restrict__ bcat,  // [1024]
    float* __restrict__ out,         // [256,1024]
    float* __restrict__ ws_f) {
  u64* W = (u64*)ws_f;
  float* MTp = (float*)(W + WMT);
  const int b = blockIdx.x, tid = threadIdx.x;
  const int w = tid >> 6, l = tid & 63;
  const int j0 = b << 2;
  const int d = w >> 1, gp = w & 1;  // LSTM pair roles
  const int k = j0 + d;              // owned dim for phases A/B

  __shared__ __align__(16) float bxA[HDIM], bhA[HDIM], bxB[HDIM], bhB[HDIM],
                                 bhC[HDIM], bsD[HDIM];
  __shared__ int fxA, fhA, fxB, fhB, fhC, fsD;
  __shared__ float pG[4], pO[4];
  __shared__ int pF[4];
  if (tid == 0) { fxA = fhA = fxB = fhB = fhC = fsD = 0; }
  if (tid < 4) pF[tid] = 0;

  // ---- static register loads: LSTM rows (gate order i,f,g,o) ----
  const int ga = gp * 2;  // this wave's two gates: ga, ga+1
  const float* WI0 = w_ih;
  const float* WH0p = w_hh;
  const float* WI1 = w_ih + (size_t)4096 * 1024;
  const float* WH1p = w_hh + (size_t)4096 * 1024;
  float wiA0[16], wiA1[16], whA0[16], whA1[16];
  float wiB0[16], wiB1[16], whB0[16], whB1[16];
#pragma unroll
  for (int i = 0; i < 16; ++i) {
    int col = l + 64 * i;
    wiA0[i] = WI0[(size_t)((ga    ) * 1024 + k) * 1024 + col];
    wiA1[i] = WI0[(size_t)((ga + 1) * 1024 + k) * 1024 + col];
    whA0[i] = WH0p[(size_t)((ga    ) * 1024 + k) * 1024 + col];
    whA1[i] = WH0p[(size_t)((ga + 1) * 1024 + k) * 1024 + col];
    wiB0[i] = WI1[(size_t)((ga    ) * 1024 + k) * 1024 + col];
    wiB1[i] = WI1[(size_t)((ga + 1) * 1024 + k) * 1024 + col];
    whB0[i] = WH1p[(size_t)((ga    ) * 1024 + k) * 1024 + col];
    whB1[i] = WH1p[(size_t)((ga + 1) * 1024 + k) * 1024 + col];
  }
  // attention row: w<4 -> enc row j0+w (score), w>=4 -> Wc2 row j0+(w-4)
  const int cd = (w < 4) ? w : (w - 4);
  const float* crp = (w < 4) ? (enc + (size_t)(j0 + cd) * 1024)
                             : (wcat + (size_t)(j0 + cd) * 2048 + 1024);
  float crow[16];
#pragma unroll
  for (int i = 0; i < 16; ++i) crow[i] = crp[l + 64 * i];
  // biases (gate-summed), cell state, output bias — all lane-uniform scalars
  float bA[4], bB[4];
#pragma unroll
  for (int g = 0; g < 4; ++g) {
    bA[g] = b_ih[g * 1024 + k] + b_hh[g * 1024 + k];
    bB[g] = b_ih[4096 + g * 1024 + k] + b_hh[4096 + g * 1024 + k];
  }
  float c0 = cell[k], c1 = cell[1024 + k];
  float bc = bcat[j0 + cd];

  // ---- pre-phase: MT[j][s] = Wc1[j]·enc[s] for j=j0..j0+3 (cooperative) ----
  {
#pragma unroll
    for (int r = 0; r < 4; ++r) {
      float* wcb = (r == 0) ? bxA : (r == 1) ? bhA : (r == 2) ? bxB : bhB;
      for (int idx = tid; idx < HDIM; idx += NTHR)
        wcb[idx] = wcat[(size_t)(j0 + r) * 2048 + idx];
    }
    __syncthreads();
#pragma unroll
    for (int rep = 0; rep < 2; ++rep) {
      int s = (w << 6) + l + (rep << 9);
      const float* er = enc + (size_t)s * 1024;
      float a0 = 0.f, a1 = 0.f, a2 = 0.f, a3 = 0.f;
      for (int hh = 0; hh < 1024; hh += 4) {
        float4 ev = *(const float4*)(er + hh);
        float4 q0 = *(const float4*)(bxA + hh);
        float4 q1 = *(const float4*)(bhA + hh);
        float4 q2 = *(const float4*)(bxB + hh);
        float4 q3 = *(const float4*)(bhB + hh);
        a0 += ev.x * q0.x + ev.y * q0.y + ev.z * q0.z + ev.w * q0.w;
        a1 += ev.x * q1.x + ev.y * q1.y + ev.z * q1.z + ev.w * q1.w;
        a2 += ev.x * q2.x + ev.y * q2.y + ev.z * q2.z + ev.w * q2.w;
        a3 += ev.x * q3.x + ev.y * q3.y + ev.z * q3.z + ev.w * q3.w;
      }
      MTp[(size_t)(j0 + 0) * 1024 + s] = a0;
      MTp[(size_t)(j0 + 1) * 1024 + s] = a1;
      MTp[(size_t)(j0 + 2) * 1024 + s] = a2;
      MTp[(size_t)(j0 + 3) * 1024 + s] = a3;
    }
    __syncthreads();
  }
  // D waves: MT row into registers (stays for the whole kernel)
  float mt[16];
  if (w >= 4) {
#pragma unroll
    for (int i = 0; i < 16; ++i)
      mt[i] = MTp[(size_t)(j0 + w - 4) * 1024 + l + 64 * i];
  }
  __syncthreads();  // flags initialized, LDS scratch free — enter dataflow loop

  float y2 = 0.f;
  for (int t = 0; t < TSTEPS; ++t) {
    const int par = t & 1;
    const int gen = t + 1;

    // ===== Phase A: layer-0 LSTM =====
    if (w == 6) {
      if (t == 0) stage_direct(hid + HDIM, bxA, &fxA, gen, l);   // x0 = h[-1]
      else        stage_poll(W + WX, t, bxA, &fxA, gen, l);
    }
    if (w == 7) {
      if (t == 0) stage_direct(hid, bhA, &fhA, gen, l);          // h0 init
      else        stage_poll(W + WH0 + (par ^ 1) * 1024, t, bhA, &fhA, gen, l);
    }
    lds_wait(&fxA, gen);
    lds_wait(&fhA, gen);
    {
      float a0 = 0.f, a1 = 0.f;
#pragma unroll
      for (int i = 0; i < 16; ++i) {
        float xv = bxA[l + 64 * i], hv = bhA[l + 64 * i];
        a0 += wiA0[i] * xv + whA0[i] * hv;
        a1 += wiA1[i] * xv + whA1[i] * hv;
      }
      a0 = wred_sum(a0);
      a1 = wred_sum(a1);
      if (gp == 1) {
        if (l == 0) { pG[d] = a0; pO[d] = a1; lds_set(&pF[d], 2 * t + 1); }
      } else if (l == 0) {
        lds_wait(&pF[d], 2 * t + 1);
        float gi = sigf(a0 + bA[0]), gf = sigf(a1 + bA[1]);
        float gg = tanhf(pG[d] + bA[2]), go = sigf(pO[d] + bA[3]);
        c0 = gf * c0 + gi * gg;
        astore64(W + WH0 + par * 1024 + k, gen, go * tanhf(c0));
      }
    }

    // ===== Phase B: layer-1 LSTM =====
    if (w == 6) stage_poll(W + WH0 + par * 1024, gen, bxB, &fxB, gen, l);
    if (w == 7) {
      if (t == 0) stage_direct(hid + HDIM, bhB, &fhB, gen, l);   // h1 init
      else        stage_poll(W + WH1 + (par ^ 1) * 1024, t, bhB, &fhB, gen, l);
    }
    lds_wait(&fxB, gen);
    lds_wait(&fhB, gen);
    {
      float a0 = 0.f, a1 = 0.f;
#pragma unroll
      for (int i = 0; i < 16; ++i) {
        float xv = bxB[l + 64 * i], hv = bhB[l + 64 * i];
        a0 += wiB0[i] * xv + whB0[i] * hv;
        a1 += wiB1[i] * xv + whB1[i] * hv;
      }
      a0 = wred_sum(a0);
      a1 = wred_sum(a1);
      if (gp == 1) {
        if (l == 0) { pG[d] = a0; pO[d] = a1; lds_set(&pF[d], 2 * t + 2); }
      } else if (l == 0) {
        lds_wait(&pF[d], 2 * t + 2);
        float gi = sigf(a0 + bB[0]), gf = sigf(a1 + bB[1]);
        float gg = tanhf(pG[d] + bB[2]), go = sigf(pO[d] + bB[3]);
        c1 = gf * c1 + gi * gg;
        astore64(W + WH1 + par * 1024 + k, gen, go * tanhf(c1));
      }
    }

    // ===== Phase C: scores (w<4) / y2 (w>=4) =====
    if (w == 6) stage_poll(W + WH1 + par * 1024, gen, bhC, &fhC, gen, l);
    lds_wait(&fhC, gen);
    {
      float p = 0.f;
#pragma unroll
      for (int i = 0; i < 16; ++i) p += crow[i] * bhC[l + 64 * i];
      p = wred_sum(p);
      if (w < 4) {
        if (l == 0) astore64(W + WSC + j0 + w, gen, p);
      } else {
        y2 = p;  // consumed by this same wave in phase D
      }
    }

    // ===== Phase D: softmax + MT dot + tanh (waves 4-7) =====
    if (w == 7) stage_poll(W + WSC, gen, bsD, &fsD, gen, l);
    if (w >= 4) {
      lds_wait(&fsD, gen);
      float sv[16];
#pragma unroll
      for (int i = 0; i < 16; ++i) sv[i] = bsD[l + 64 * i];
      float mx = sv[0];
#pragma unroll
      for (int i = 1; i < 16; ++i) mx = fmaxf(mx, sv[i]);
      mx = wred_max(mx);
      float den = 0.f, num = 0.f;
#pragma unroll
      for (int i = 0; i < 16; ++i) {
        float e = __expf(sv[i] - mx);
        den += e;
        num += e * mt[i];
      }
      den = wred_sum(den);
      num = wred_sum(num);
      if (l == 0) {
        int j = j0 + (w - 4);
        float val = tanhf(num / den + y2 + bc);
        astore64(W + WX + j, gen, val);      // next step's x
        out[(size_t)t * HDIM + j] = val;     // kernel output
      }
    }
  }
}

extern "C" void kernel_launch(void* const* d_in, const int* in_sizes, int n_in,
                              void* d_out, int out_size, void* d_ws, size_t ws_size,
                              hipStream_t stream) {
  // d_in: 0 input_sequence (UNUSED by reference), 1 encoder_out, 2 hidden_state,
  //       3 cell_state, 4 w_ih, 5 w_hh, 6 b_ih, 7 b_hh, 8 w_concat, 9 b_concat
  const float* enc  = (const float*)d_in[1];
  const float* hid  = (const float*)d_in[2];
  const float* cel  = (const float*)d_in[3];
  const float* wih  = (const float*)d_in[4];
  const float* whh  = (const float*)d_in[5];
  const float* bih  = (const float*)d_in[6];
  const float* bhh  = (const float*)d_in[7];
  const float* wcat = (const float*)d_in[8];
  const float* bcat = (const float*)d_in[9];
  float* out = (float*)d_out;
  float* ws  = (float*)d_ws;

  hipLaunchKernelGGL(decoder_persist, dim3(NBLK), dim3(NTHR), 0, stream,
                     enc, hid, cel, wih, whh, bih, bhh, wcat, bcat, out, ws);
}

// Round 4
// 5140.252 us; speedup vs baseline: 1.5114x; 1.5114x over previous
//
#include <hip/hip_runtime.h>
#include <cstdint>
#include <cstddef>

// ---------------------------------------------------------------------------
// Register-resident persistent-RNN decoder: 2-layer LSTM (H=1024) + Luong dot
// attention, T=256 sequential steps. 256 blocks x 512 threads (8 waves),
// __launch_bounds__(512,2) (<=256 VGPR, 1 block/CU -> co-residency).
// Weights live in VGPRs for the whole kernel (round-3-proven: FETCH ~104MB).
//
// Cross-block exchange: MAILBOX REPLICATION. Per phase each block packs its 4
// output dims into one 32B packet of (tag,val) u64 pairs and stores it to 8
// region copies. Each block polls ONLY copy (b%8) -> 32 pollers/line instead
// of 256 (round-3's failure: per-line poll storm at the MALL). Detection and
// data arrive in the same 8B atomic; no grid barrier, no aggregator.
// Regions: RA carries h0' (tag 4t+1) then scores (4t+3); RB carries h1'
// (4t+2) then x (4t+4). Overwrite safety proven via the A->B->C->D step
// dependency chain. Poison 0xAA = negative tag, never matches.
//
// Wave roles (dims j0=4b..j0+3; pair 2d/2d+1 splits gates i,f / g,o):
//   even waves: combine+publish-value for dim d   odd waves: partial senders
//   w6: packet publisher for A and B    w3: C-score d3 + scores publisher
//   w7: D dim3 + x publisher            w5: gathers h0'  w3: gathers h1'
//   w1: gathers scores                  w0: gathers x (for next step)
//   waves 4-7: phase D (softmax + reg-MT dot + tanh), dim w-4
// Main loop has ZERO __syncthreads; intra-block sync via LDS flags only.
// ---------------------------------------------------------------------------

#define TSTEPS 256
#define HDIM   1024
#define NBLK   256
#define NTHR   512
#define NCOPY  8

typedef unsigned long long u64;

// ws layout in u64 units
#define REGA 0        // 8 copies x 256 packets x 4 pairs = 8192 u64 (64 KB)
#define REGB 8192
#define WMT  16384    // MT f32[1024*1024] after regions

__device__ __forceinline__ float wred_sum(float v) {
#pragma unroll
  for (int m = 32; m >= 1; m >>= 1) v += __shfl_xor(v, m, 64);
  return v;
}
__device__ __forceinline__ float wred_max(float v) {
#pragma unroll
  for (int m = 32; m >= 1; m >>= 1) v = fmaxf(v, __shfl_xor(v, m, 64));
  return v;
}
__device__ __forceinline__ void pub_store(u64* p, u64 v) {
  __hip_atomic_store(p, v, __ATOMIC_RELAXED, __HIP_MEMORY_SCOPE_AGENT);
}
__device__ __forceinline__ u64 pub_load(const u64* p) {
  return __hip_atomic_load(p, __ATOMIC_RELAXED, __HIP_MEMORY_SCOPE_AGENT);
}
__device__ __forceinline__ void lds_set(int* f, int v) {
  __hip_atomic_store(f, v, __ATOMIC_RELEASE, __HIP_MEMORY_SCOPE_WORKGROUP);
}
__device__ __forceinline__ void lds_wait(int* f, int v) {
  while (__hip_atomic_load(f, __ATOMIC_ACQUIRE, __HIP_MEMORY_SCOPE_WORKGROUP) < v) {}
}
__device__ __forceinline__ float sigf(float x) { return 1.f / (1.f + __expf(-x)); }

// Poll 256 packets (4 per lane) of (tag,val) pairs in one region copy;
// deposit the 1024-float vector to LDS; release flag. Miss-mask avoids
// re-reading found slots.
__device__ __forceinline__ void gather(const u64* base, int tag, float* buf,
                                       int* flag, int fval, int l) {
  float v[16];
  unsigned miss = 0xffffu;
  while (miss) {
#pragma unroll
    for (int i = 0; i < 4; ++i) {
      const u64* pk = base + (size_t)(l + 64 * i) * 4;
#pragma unroll
      for (int dd = 0; dd < 4; ++dd) {
        int bit = 4 * i + dd;
        if (miss & (1u << bit)) {
          u64 x = pub_load(pk + dd);
          if ((int)(x >> 32) == tag) {
            v[bit] = __uint_as_float((unsigned)x);
            miss &= ~(1u << bit);
          }
        }
      }
    }
    if (miss) __builtin_amdgcn_s_sleep(1);
  }
#pragma unroll
  for (int i = 0; i < 4; ++i)
    *(float4*)(buf + 4 * (l + 64 * i)) =
        make_float4(v[4 * i], v[4 * i + 1], v[4 * i + 2], v[4 * i + 3]);
  lds_set(flag, fval);
}

// One wave publishes the block's 4-value packet to all 8 copies.
// lane m<32: copy m>>2, pair m&3.
__device__ __forceinline__ void publish(u64* region, int b, int tag,
                                        const float* shpub, int l) {
  if (l < 32) {
    u64 pk = ((u64)(unsigned)tag << 32) |
             (u64)(unsigned)__float_as_uint(shpub[l & 3]);
    pub_store(region + (size_t)(l >> 2) * 1024 + (size_t)b * 4 + (l & 3), pk);
  }
}

// A/B LSTM phase: 8 waves, pair (2d even: gates i,f + combine) (2d+1: g,o).
#define LSTM_PHASE(WIA, WIB, WHA, WHB, XBUF, HBUF, SHG, PF, CF, BIAS, CST, PUBTAG, REGION) \
  {                                                                            \
    float a0 = 0.f, a1 = 0.f;                                                  \
    _Pragma("unroll")                                                          \
    for (int i = 0; i < 16; ++i) {                                             \
      float xv = (XBUF)[l + 64 * i], hv = (HBUF)[l + 64 * i];                  \
      a0 += WIA[i] * xv + WHA[i] * hv;                                         \
      a1 += WIB[i] * xv + WHB[i] * hv;                                         \
    }                                                                          \
    a0 = wred_sum(a0);                                                         \
    a1 = wred_sum(a1);                                                         \
    if (gp == 1) {                                                             \
      if (l == 0) { SHG[d][0] = a0; SHG[d][1] = a1; lds_set(&PF[d], gen); }    \
    } else {                                                                   \
      lds_wait(&PF[d], gen);                                                   \
      float gi = sigf(a0 + BIAS[0]), gf = sigf(a1 + BIAS[1]);                  \
      float gg = tanhf(SHG[d][0] + BIAS[2]), go = sigf(SHG[d][1] + BIAS[3]);   \
      CST = gf * CST + gi * gg;                                                \
      float hn = go * tanhf(CST);                                              \
      if (l == 0) { sh_pub[d] = hn; lds_set(&CF[d], gen); }                    \
    }                                                                          \
    if (w == 6) {                                                              \
      lds_wait(&CF[0], gen); lds_wait(&CF[1], gen);                            \
      lds_wait(&CF[2], gen); lds_wait(&CF[3], gen);                            \
      publish(REGION, b, PUBTAG, sh_pub, l);                                   \
    }                                                                          \
  }

__global__ void __launch_bounds__(NTHR, 2) decoder_persist(
    const float* __restrict__ enc,   // [1024,1024]
    const float* __restrict__ hid,   // [2,1024]
    const float* __restrict__ cell,  // [2,1024]
    const float* __restrict__ w_ih,  // [2,4096,1024]
    const float* __restrict__ w_hh,  // [2,4096,1024]
    const float* __restrict__ b_ih,  // [2,4096]
    const float* __restrict__ b_hh,  // [2,4096]
    const float* __restrict__ wcat,  // [1024,2048]
    const float* __restrict__ bcat,  // [1024]
    float* __restrict__ out,         // [256,1024]
    float* __restrict__ ws_f) {
  u64* W  = (u64*)ws_f;
  u64* RA = W + REGA;
  u64* RB = W + REGB;
  float* MTp = (float*)(W + WMT);
  const int b = blockIdx.x, tid = threadIdx.x;
  const int w = tid >> 6, l = tid & 63;
  const int j0 = b << 2;
  const int d = w >> 1, gp = w & 1, ga = gp << 1;  // A/B pair roles
  const int k = j0 + d;
  const int cp = b & (NCOPY - 1);
  const u64* RAc = RA + (size_t)cp * 1024;
  const u64* RBc = RB + (size_t)cp * 1024;

  __shared__ __align__(16) float bx[HDIM], bh0[2][HDIM], bh1[2][HDIM], bsc[HDIM];
  __shared__ float sh_gA[4][2], sh_gB[4][2], sh_pub[4], sh_pub2[4], sh_pubD[4];
  __shared__ int pFA[4], pFB[4], cA[4], cB[4], cC[4], cD[4];
  __shared__ int fx, f0, f1, fs;

  // ---- static register weights (gate order i,f,g,o) ----
  const float* WI0 = w_ih;
  const float* WH0 = w_hh;
  const float* WI1 = w_ih + (size_t)4096 * 1024;
  const float* WH1 = w_hh + (size_t)4096 * 1024;
  float wiA0[16], wiA1[16], whA0[16], whA1[16];
  float wiB0[16], wiB1[16], whB0[16], whB1[16];
#pragma unroll
  for (int i = 0; i < 16; ++i) {
    int col = l + 64 * i;
    wiA0[i] = WI0[(size_t)((ga    ) * 1024 + k) * 1024 + col];
    wiA1[i] = WI0[(size_t)((ga + 1) * 1024 + k) * 1024 + col];
    whA0[i] = WH0[(size_t)((ga    ) * 1024 + k) * 1024 + col];
    whA1[i] = WH0[(size_t)((ga + 1) * 1024 + k) * 1024 + col];
    wiB0[i] = WI1[(size_t)((ga    ) * 1024 + k) * 1024 + col];
    wiB1[i] = WI1[(size_t)((ga + 1) * 1024 + k) * 1024 + col];
    whB0[i] = WH1[(size_t)((ga    ) * 1024 + k) * 1024 + col];
    whB1[i] = WH1[(size_t)((ga + 1) * 1024 + k) * 1024 + col];
  }
  // attention row: w<4 -> enc row j0+w (scores); w>=4 -> Wc2 row j0+(w-4)
  const int cd = (w < 4) ? w : (w - 4);
  const float* crp = (w < 4) ? (enc + (size_t)(j0 + cd) * 1024)
                             : (wcat + (size_t)(j0 + cd) * 2048 + 1024);
  float crow[16];
#pragma unroll
  for (int i = 0; i < 16; ++i) crow[i] = crp[l + 64 * i];
  float bA[4], bB[4];
  if (gp == 0) {
#pragma unroll
    for (int g = 0; g < 4; ++g) {
      bA[g] = b_ih[g * 1024 + k] + b_hh[g * 1024 + k];
      bB[g] = b_ih[4096 + g * 1024 + k] + b_hh[4096 + g * 1024 + k];
    }
  }
  float cst0 = cell[k], cst1 = cell[HDIM + k];  // used by even waves
  float bc = (w >= 4) ? bcat[j0 + cd] : 0.f;

  // ---- pre-phase: MT[j][s] = Wc1[j]·enc[s], block owns j = j0..j0+3 ----
  {
    for (int idx = tid; idx < HDIM; idx += NTHR) {
      bh0[0][idx] = wcat[(size_t)(j0 + 0) * 2048 + idx];
      bh0[1][idx] = wcat[(size_t)(j0 + 1) * 2048 + idx];
      bh1[0][idx] = wcat[(size_t)(j0 + 2) * 2048 + idx];
      bh1[1][idx] = wcat[(size_t)(j0 + 3) * 2048 + idx];
    }
    __syncthreads();
#pragma unroll
    for (int rep = 0; rep < 2; ++rep) {
      int s = (w << 6) + l + (rep << 9);
      const float* er = enc + (size_t)s * 1024;
      float a0 = 0.f, a1 = 0.f, a2 = 0.f, a3 = 0.f;
      for (int hh = 0; hh < 1024; hh += 4) {
        float4 ev = *(const float4*)(er + hh);
        float4 q0 = *(const float4*)(&bh0[0][hh]);
        float4 q1 = *(const float4*)(&bh0[1][hh]);
        float4 q2 = *(const float4*)(&bh1[0][hh]);
        float4 q3 = *(const float4*)(&bh1[1][hh]);
        a0 += ev.x * q0.x + ev.y * q0.y + ev.z * q0.z + ev.w * q0.w;
        a1 += ev.x * q1.x + ev.y * q1.y + ev.z * q1.z + ev.w * q1.w;
        a2 += ev.x * q2.x + ev.y * q2.y + ev.z * q2.z + ev.w * q2.w;
        a3 += ev.x * q3.x + ev.y * q3.y + ev.z * q3.z + ev.w * q3.w;
      }
      MTp[(size_t)(j0 + 0) * 1024 + s] = a0;
      MTp[(size_t)(j0 + 1) * 1024 + s] = a1;
      MTp[(size_t)(j0 + 2) * 1024 + s] = a2;
      MTp[(size_t)(j0 + 3) * 1024 + s] = a3;
    }
    __syncthreads();
  }
  float mt[16];
  if (w >= 4) {
#pragma unroll
    for (int i = 0; i < 16; ++i)
      mt[i] = MTp[(size_t)(j0 + cd) * 1024 + l + 64 * i];
  }
  // preload initial vectors + flag init
  for (int idx = tid; idx < HDIM; idx += NTHR) {
    bx[idx]     = hid[HDIM + idx];  // x(0) = hidden_state[-1]
    bh0[1][idx] = hid[idx];         // h0(-1)   (parity: A(0) reads bh0[1])
    bh1[1][idx] = hid[HDIM + idx];  // h1(-1)
  }
  if (tid == 0) { fx = 1; f0 = 0; f1 = 0; fs = 0; }
  if (tid < 4) { pFA[tid] = 0; pFB[tid] = 0; cA[tid] = 0; cB[tid] = 0;
                 cC[tid] = 0; cD[tid] = 0; }
  __syncthreads();

  for (int t = 0; t < TSTEPS; ++t) {
    const int gen = t + 1;
    const int par = t & 1, parp = par ^ 1;

    // ===== Phase A: layer-0 LSTM =====
    lds_wait(&fx, gen);  // x(t) in bx
    LSTM_PHASE(wiA0, wiA1, whA0, whA1, bx, bh0[parp], sh_gA, pFA, cA, bA, cst0,
               4 * t + 1, RA);
    if (w == 5) gather(RAc, 4 * t + 1, bh0[par], &f0, gen, l);

    // ===== Phase B: layer-1 LSTM =====
    lds_wait(&f0, gen);  // h0'(t) in bh0[par]
    LSTM_PHASE(wiB0, wiB1, whB0, whB1, bh0[par], bh1[parp], sh_gB, pFB, cB, bB,
               cst1, 4 * t + 2, RB);
    if (w == 3) gather(RBc, 4 * t + 2, bh1[par], &f1, gen, l);

    // ===== Phase C: scores (w<4, publish) / y2 (w>=4, keep local) =====
    lds_wait(&f1, gen);  // h1'(t) in bh1[par]
    float y2v = 0.f;
    {
      float p = 0.f;
#pragma unroll
      for (int i = 0; i < 16; ++i) p += crow[i] * bh1[par][l + 64 * i];
      p = wred_sum(p);
      if (w < 4) {
        if (l == 0) { sh_pub2[w] = p; lds_set(&cC[w], gen); }
        if (w == 3) {
          lds_wait(&cC[0], gen); lds_wait(&cC[1], gen);
          lds_wait(&cC[2], gen); lds_wait(&cC[3], gen);
          publish(RA, b, 4 * t + 3, sh_pub2, l);
        }
      } else {
        y2v = p;
      }
    }
    if (w == 1) gather(RAc, 4 * t + 3, bsc, &fs, gen, l);

    // ===== Phase D: softmax + reg-MT dot + tanh (waves 4-7) =====
    if (w >= 4) {
      lds_wait(&fs, gen);
      float sv[16];
#pragma unroll
      for (int i = 0; i < 16; ++i) sv[i] = bsc[l + 64 * i];
      float mx = sv[0];
#pragma unroll
      for (int i = 1; i < 16; ++i) mx = fmaxf(mx, sv[i]);
      mx = wred_max(mx);
      float den = 0.f, num = 0.f;
#pragma unroll
      for (int i = 0; i < 16; ++i) {
        float e = __expf(sv[i] - mx);
        den += e;
        num += e * mt[i];
      }
      den = wred_sum(den);
      num = wred_sum(num);
      float val = tanhf(num / den + y2v + bc);
      if (l == 0) {
        out[(size_t)t * HDIM + j0 + cd] = val;
        sh_pubD[cd] = val;
        lds_set(&cD[cd], gen);
      }
      if (w == 7) {
        lds_wait(&cD[0], gen); lds_wait(&cD[1], gen);
        lds_wait(&cD[2], gen); lds_wait(&cD[3], gen);
        publish(RB, b, 4 * t + 4, sh_pubD, l);
      }
    }
    if (w == 0) gather(RBc, 4 * t + 4, bx, &fx, t + 2, l);  // x(t+1)
  }
}

extern "C" void kernel_launch(void* const* d_in, const int* in_sizes, int n_in,
                              void* d_out, int out_size, void* d_ws, size_t ws_size,
                              hipStream_t stream) {
  // d_in: 0 input_sequence (UNUSED by reference), 1 encoder_out, 2 hidden_state,
  //       3 cell_state, 4 w_ih, 5 w_hh, 6 b_ih, 7 b_hh, 8 w_concat, 9 b_concat
  const float* enc  = (const float*)d_in[1];
  const float* hid  = (const float*)d_in[2];
  const float* cel  = (const float*)d_in[3];
  const float* wih  = (const float*)d_in[4];
  const float* whh  = (const float*)d_in[5];
  const float* bih  = (const float*)d_in[6];
  const float* bhh  = (const float*)d_in[7];
  const float* wcat = (const float*)d_in[8];
  const float* bcat = (const float*)d_in[9];
  float* out = (float*)d_out;
  float* ws  = (float*)d_ws;

  hipLaunchKernelGGL(decoder_persist, dim3(NBLK), dim3(NTHR), 0, stream,
                     enc, hid, cel, wih, whh, bih, bhh, wcat, bcat, out, ws);
}

// Round 5
// 4466.992 us; speedup vs baseline: 1.7392x; 1.1507x over previous
//
#include <hip/hip_runtime.h>
#include <cstdint>
#include <cstddef>

// ---------------------------------------------------------------------------
// Chunked-dataflow persistent-RNN decoder: 2-layer LSTM (H=1024) + Luong dot
// attention, T=256 sequential steps. 256 blocks x 512 threads (8 waves),
// __launch_bounds__(512,2): <=256 VGPR, all blocks co-resident.
//
// Wave roles per block (dims k = 4b+v):
//   waves 0-3 (v=w):   layer-0 LSTM dim k, ALL 4 gates (128 weight VGPRs);
//                      also gather h1' chunk v (for C) and scores chunk v (D).
//   waves 4-7 (u=w-4): layer-1 LSTM dim k (128 VGPRs) + enc score row k +
//                      Wc2 row k + MT row k (+48 VGPRs); phase C (score s=k,
//                      y2_k) and phase D (flash softmax + MT dot + tanh, dim k);
//                      also gather x chunk u and h0' chunk u.
//
// Communication: 4 mailbox regions (x, h0', h1', scores), each 8 replicated
// copies x 1024 dims x 8B (tag,val). Producer wave publishes per-dim the
// moment its wred completes (lanes 0-7 -> 8 copies, no intra-block combine).
// Consumers gather per 256-dim CHUNK (4 gather waves/vector, 4 slots/lane) ->
// LDS + chunk flag; compute consumes chunks progressively, so the 256-block
// straggler tail overlaps with dot-product compute. Recurrent (h-side) matvec
// halves are precomputed from parity LDS before polling. Flash-style per-lane
// online softmax consumes score chunks as they arrive.
//
// Overwrite safety of single-buffered regions follows from the global step
// dependency chain (x->A->h0'->B->h1'->C->scores->D->x): any re-publish of a
// slot is transitively gated on every block having consumed the old value.
// LDS h0/h1 are parity double-buffered (deposits of step t+1 race A(t+1)'s
// recurrent reads of step t otherwise). 0xAA poison = negative tag. Zero
// __syncthreads in the main loop.
// ---------------------------------------------------------------------------

#define TSTEPS 256
#define HDIM   1024
#define NBLK   256
#define NTHR   512
#define NCOPY  8

typedef unsigned long long u64;

// ws layout in u64 units: 4 regions x 8 copies x 1024 dims
#define RX_OFF   0
#define RH0_OFF  8192
#define RH1_OFF  16384
#define RS_OFF   24576
#define WMT_OFF  32768   // MT f32[1024*1024] after regions (byte 256K)

__device__ __forceinline__ float wred_sum(float v) {
#pragma unroll
  for (int m = 32; m >= 1; m >>= 1) v += __shfl_xor(v, m, 64);
  return v;
}
__device__ __forceinline__ float wred_max(float v) {
#pragma unroll
  for (int m = 32; m >= 1; m >>= 1) v = fmaxf(v, __shfl_xor(v, m, 64));
  return v;
}
__device__ __forceinline__ void pub_store(u64* p, u64 v) {
  __hip_atomic_store(p, v, __ATOMIC_RELAXED, __HIP_MEMORY_SCOPE_AGENT);
}
__device__ __forceinline__ u64 pub_load(const u64* p) {
  return __hip_atomic_load(p, __ATOMIC_RELAXED, __HIP_MEMORY_SCOPE_AGENT);
}
__device__ __forceinline__ void lds_set(int* f, int v) {
  __hip_atomic_store(f, v, __ATOMIC_RELEASE, __HIP_MEMORY_SCOPE_WORKGROUP);
}
__device__ __forceinline__ void lds_wait(int* f, int v) {
  while (__hip_atomic_load(f, __ATOMIC_ACQUIRE, __HIP_MEMORY_SCOPE_WORKGROUP) < v) {}
}
__device__ __forceinline__ float sigf(float x) { return 1.f / (1.f + __expf(-x)); }
__device__ __forceinline__ u64 pack(int tag, float v) {
  return ((u64)(unsigned)tag << 32) | (u64)(unsigned)__float_as_uint(v);
}

// publish one dim's value to all 8 copies (value is lane-uniform post-wred)
__device__ __forceinline__ void publish(u64* rbase, int k, int tag, float v, int l) {
  if (l < 8) pub_store(rbase + (size_t)l * 1024 + k, pack(tag, v));
}

// gather 4 consecutive slots (this lane's share of a 256-dim chunk), deposit
// as float4 to LDS, then release the chunk flag. slot0/dst4 pre-offset.
__device__ __forceinline__ void gather(const u64* slot0, int tag, float* dst4,
                                       int* flag) {
  float v0 = 0.f, v1 = 0.f, v2 = 0.f, v3 = 0.f;
  unsigned miss = 0xFu;
  while (miss) {
    if (miss & 1u) { u64 x = pub_load(slot0 + 0);
      if ((int)(x >> 32) == tag) { v0 = __uint_as_float((unsigned)x); miss &= ~1u; } }
    if (miss & 2u) { u64 x = pub_load(slot0 + 1);
      if ((int)(x >> 32) == tag) { v1 = __uint_as_float((unsigned)x); miss &= ~2u; } }
    if (miss & 4u) { u64 x = pub_load(slot0 + 2);
      if ((int)(x >> 32) == tag) { v2 = __uint_as_float((unsigned)x); miss &= ~4u; } }
    if (miss & 8u) { u64 x = pub_load(slot0 + 3);
      if ((int)(x >> 32) == tag) { v3 = __uint_as_float((unsigned)x); miss &= ~8u; } }
    if (miss == 0xFu) __builtin_amdgcn_s_sleep(2);
  }
  float4 q; q.x = v0; q.y = v1; q.z = v2; q.w = v3;
  *(float4*)dst4 = q;
  lds_set(flag, tag);
}

__global__ void __launch_bounds__(NTHR, 2) decoder_persist(
    const float* __restrict__ enc,   // [1024,1024]
    const float* __restrict__ hid,   // [2,1024]
    const float* __restrict__ cell,  // [2,1024]
    const float* __restrict__ w_ih,  // [2,4096,1024]
    const float* __restrict__ w_hh,  // [2,4096,1024]
    const float* __restrict__ b_ih,  // [2,4096]
    const float* __restrict__ b_hh,  // [2,4096]
    const float* __restrict__ wcat,  // [1024,2048]
    const float* __restrict__ bcat,  // [1024]
    float* __restrict__ out,         // [256,1024]
    float* __restrict__ ws_f) {
  u64* W = (u64*)ws_f;
  float* MTp = (float*)(W + WMT_OFF);
  const int b = blockIdx.x, tid = threadIdx.x;
  const int w = tid >> 6, l = tid & 63;
  const int j0 = b << 2;
  const int k = j0 + (w & 3);        // owned dim
  const int cp = b & (NCOPY - 1);    // polled copy
  // region pointers
  u64* RXb  = W + RX_OFF;   const u64* RXc  = RXb  + (size_t)cp * 1024;
  u64* RH0b = W + RH0_OFF;  const u64* RH0c = RH0b + (size_t)cp * 1024;
  u64* RH1b = W + RH1_OFF;  const u64* RH1c = RH1b + (size_t)cp * 1024;
  u64* RSb  = W + RS_OFF;   const u64* RSc  = RSb  + (size_t)cp * 1024;

  __shared__ __align__(16) float bx[HDIM], bh0[2][HDIM], bh1[2][HDIM], bsc[HDIM];
  __shared__ int fx[4], fh0[4], fh1[4], fsc[4];

  // ---- pre-phase: MT[j][s] = Wc1[j]*enc[s] for j = j0..j0+3 (cooperative)
  {
    for (int idx = tid; idx < HDIM; idx += NTHR) {
      bh0[0][idx] = wcat[(size_t)(j0 + 0) * 2048 + idx];
      bh0[1][idx] = wcat[(size_t)(j0 + 1) * 2048 + idx];
      bh1[0][idx] = wcat[(size_t)(j0 + 2) * 2048 + idx];
      bh1[1][idx] = wcat[(size_t)(j0 + 3) * 2048 + idx];
    }
    __syncthreads();
#pragma unroll
    for (int rep = 0; rep < 2; ++rep) {
      int s = (w << 6) + l + (rep << 9);
      const float* er = enc + (size_t)s * 1024;
      float a0 = 0.f, a1 = 0.f, a2 = 0.f, a3 = 0.f;
      for (int hh = 0; hh < 1024; hh += 4) {
        float4 ev = *(const float4*)(er + hh);
        float4 q0 = *(const float4*)(&bh0[0][hh]);
        float4 q1 = *(const float4*)(&bh0[1][hh]);
        float4 q2 = *(const float4*)(&bh1[0][hh]);
        float4 q3 = *(const float4*)(&bh1[1][hh]);
        a0 += ev.x * q0.x + ev.y * q0.y + ev.z * q0.z + ev.w * q0.w;
        a1 += ev.x * q1.x + ev.y * q1.y + ev.z * q1.z + ev.w * q1.w;
        a2 += ev.x * q2.x + ev.y * q2.y + ev.z * q2.z + ev.w * q2.w;
        a3 += ev.x * q3.x + ev.y * q3.y + ev.z * q3.z + ev.w * q3.w;
      }
      MTp[(size_t)(j0 + 0) * 1024 + s] = a0;
      MTp[(size_t)(j0 + 1) * 1024 + s] = a1;
      MTp[(size_t)(j0 + 2) * 1024 + s] = a2;
      MTp[(size_t)(j0 + 3) * 1024 + s] = a3;
    }
    __syncthreads();
  }
  // preload initial vectors (x(0)=h1(-1)=hid[1], h0(-1)=hid[0]), init flags
  for (int idx = tid; idx < HDIM; idx += NTHR) {
    bx[idx]     = hid[HDIM + idx];
    bh0[1][idx] = hid[idx];
    bh1[1][idx] = hid[HDIM + idx];
  }
  if (tid < 4) { fx[tid] = 0; fh0[tid] = 0; fh1[tid] = 0; fsc[tid] = 0; }
  __syncthreads();

  if (w < 4) {
    // ================= L0 waves: layer-0 LSTM dim k; gather h1'/scores =====
    const int v = w;  // chunk id
    float wiA[4][16], whA[4][16];
#pragma unroll
    for (int g = 0; g < 4; ++g)
#pragma unroll
      for (int i = 0; i < 16; ++i) {
        wiA[g][i] = w_ih[(size_t)(g * 1024 + k) * 1024 + l + 64 * i];
        whA[g][i] = w_hh[(size_t)(g * 1024 + k) * 1024 + l + 64 * i];
      }
    float bAg[4];
#pragma unroll
    for (int g = 0; g < 4; ++g)
      bAg[g] = b_ih[g * 1024 + k] + b_hh[g * 1024 + k];
    float c0 = cell[k];

    for (int t = 0; t < TSTEPS; ++t) {
      const int gen = t + 1, par = t & 1, parp = par ^ 1;
      // recurrent h-side (previous step's h0, parity LDS)
      lds_wait(&fh0[0], t); lds_wait(&fh0[1], t);
      lds_wait(&fh0[2], t); lds_wait(&fh0[3], t);
      float a0 = 0.f, a1 = 0.f, a2 = 0.f, a3 = 0.f;
#pragma unroll
      for (int i = 0; i < 16; ++i) {
        float hv = bh0[parp][l + 64 * i];
        a0 += whA[0][i] * hv; a1 += whA[1][i] * hv;
        a2 += whA[2][i] * hv; a3 += whA[3][i] * hv;
      }
      // x-side, chunk-progressive
#pragma unroll
      for (int c = 0; c < 4; ++c) {
        lds_wait(&fx[c], t);
#pragma unroll
        for (int i2 = 0; i2 < 4; ++i2) {
          float xv = bx[256 * c + l + 64 * i2];
          a0 += wiA[0][4 * c + i2] * xv; a1 += wiA[1][4 * c + i2] * xv;
          a2 += wiA[2][4 * c + i2] * xv; a3 += wiA[3][4 * c + i2] * xv;
        }
      }
      a0 = wred_sum(a0); a1 = wred_sum(a1);
      a2 = wred_sum(a2); a3 = wred_sum(a3);
      float gi = sigf(a0 + bAg[0]), gf = sigf(a1 + bAg[1]);
      float gg = tanhf(a2 + bAg[2]), go = sigf(a3 + bAg[3]);
      c0 = gf * c0 + gi * gg;
      publish(RH0b, k, gen, go * tanhf(c0), l);
      // gather h1' chunk v (produced by B(t)) then scores chunk v (C(t))
      gather(RH1c + 256 * v + 4 * l, gen, &bh1[par][256 * v + 4 * l], &fh1[v]);
      gather(RSc + 256 * v + 4 * l, gen, &bsc[256 * v + 4 * l], &fsc[v]);
    }
  } else {
    // ====== L1 waves: layer-1 LSTM dim k + score s=k + y2_k + phase D ======
    const int u = w - 4;  // chunk id
    const float* WI1 = w_ih + (size_t)4096 * 1024;
    const float* WH1 = w_hh + (size_t)4096 * 1024;
    float wiB[4][16], whB[4][16], encr[16], wc2r[16], mtr[16];
#pragma unroll
    for (int g = 0; g < 4; ++g)
#pragma unroll
      for (int i = 0; i < 16; ++i) {
        wiB[g][i] = WI1[(size_t)(g * 1024 + k) * 1024 + l + 64 * i];
        whB[g][i] = WH1[(size_t)(g * 1024 + k) * 1024 + l + 64 * i];
      }
#pragma unroll
    for (int i = 0; i < 16; ++i) {
      encr[i] = enc[(size_t)k * 1024 + l + 64 * i];
      wc2r[i] = wcat[(size_t)k * 2048 + 1024 + l + 64 * i];
      mtr[i]  = MTp[(size_t)k * 1024 + l + 64 * i];
    }
    float bBg[4];
#pragma unroll
    for (int g = 0; g < 4; ++g)
      bBg[g] = b_ih[4096 + g * 1024 + k] + b_hh[4096 + g * 1024 + k];
    float c1 = cell[HDIM + k];
    const float bcv = bcat[k];

    for (int t = 0; t < TSTEPS; ++t) {
      const int gen = t + 1, par = t & 1, parp = par ^ 1;
      // gather x(t) chunk u (published by D(t-1), tag t); t=0 preloaded
      if (t > 0)
        gather(RXc + 256 * u + 4 * l, t, &bx[256 * u + 4 * l], &fx[u]);
      // B recurrent h-side (previous h1, parity LDS)
      lds_wait(&fh1[0], t); lds_wait(&fh1[1], t);
      lds_wait(&fh1[2], t); lds_wait(&fh1[3], t);
      float a0 = 0.f, a1 = 0.f, a2 = 0.f, a3 = 0.f;
#pragma unroll
      for (int i = 0; i < 16; ++i) {
        float hv = bh1[parp][l + 64 * i];
        a0 += whB[0][i] * hv; a1 += whB[1][i] * hv;
        a2 += whB[2][i] * hv; a3 += whB[3][i] * hv;
      }
      // gather h0'(t) chunk u (published by A(t) as it lands)
      gather(RH0c + 256 * u + 4 * l, gen, &bh0[par][256 * u + 4 * l], &fh0[u]);
      // B x-side, chunk-progressive over h0'(t)
#pragma unroll
      for (int c = 0; c < 4; ++c) {
        lds_wait(&fh0[c], gen);
#pragma unroll
        for (int i2 = 0; i2 < 4; ++i2) {
          float xv = bh0[par][256 * c + l + 64 * i2];
          a0 += wiB[0][4 * c + i2] * xv; a1 += wiB[1][4 * c + i2] * xv;
          a2 += wiB[2][4 * c + i2] * xv; a3 += wiB[3][4 * c + i2] * xv;
        }
      }
      a0 = wred_sum(a0); a1 = wred_sum(a1);
      a2 = wred_sum(a2); a3 = wred_sum(a3);
      float gi = sigf(a0 + bBg[0]), gf = sigf(a1 + bBg[1]);
      float gg = tanhf(a2 + bBg[2]), go = sigf(a3 + bBg[3]);
      c1 = gf * c1 + gi * gg;
      publish(RH1b, k, gen, go * tanhf(c1), l);
      // C: score s=k and y2_k, chunk-progressive over h1'(t)
      float sc = 0.f, y2 = 0.f;
#pragma unroll
      for (int c = 0; c < 4; ++c) {
        lds_wait(&fh1[c], gen);
#pragma unroll
        for (int i2 = 0; i2 < 4; ++i2) {
          float hv = bh1[par][256 * c + l + 64 * i2];
          sc += encr[4 * c + i2] * hv;
          y2 += wc2r[4 * c + i2] * hv;
        }
      }
      sc = wred_sum(sc); y2 = wred_sum(y2);
      publish(RSb, k, gen, sc, l);
      // D: flash per-lane softmax over score chunks + MT dot
      float m = -1e30f, den = 0.f, num = 0.f;
#pragma unroll
      for (int c = 0; c < 4; ++c) {
        lds_wait(&fsc[c], gen);
#pragma unroll
        for (int i2 = 0; i2 < 4; ++i2) {
          float s = bsc[256 * c + l + 64 * i2];
          if (s > m) {
            float r = __expf(m - s);
            den *= r; num *= r; m = s;
          }
          float e = __expf(s - m);
          den += e; num += e * mtr[4 * c + i2];
        }
      }
      float M = wred_max(m);
      float r = __expf(m - M);
      den = wred_sum(den * r);
      num = wred_sum(num * r);
      float val = tanhf(num / den + y2 + bcv);
      if (l == 0) out[(size_t)t * HDIM + k] = val;
      publish(RXb, k, gen, val, l);  // x(t+1), polled with tag t+1 = gen
    }
  }
}

extern "C" void kernel_launch(void* const* d_in, const int* in_sizes, int n_in,
                              void* d_out, int out_size, void* d_ws, size_t ws_size,
                              hipStream_t stream) {
  // d_in: 0 input_sequence (UNUSED by reference), 1 encoder_out, 2 hidden_state,
  //       3 cell_state, 4 w_ih, 5 w_hh, 6 b_ih, 7 b_hh, 8 w_concat, 9 b_concat
  const float* enc  = (const float*)d_in[1];
  const float* hid  = (const float*)d_in[2];
  const float* cel  = (const float*)d_in[3];
  const float* wih  = (const float*)d_in[4];
  const float* whh  = (const float*)d_in[5];
  const float* bih  = (const float*)d_in[6];
  const float* bhh  = (const float*)d_in[7];
  const float* wcat = (const float*)d_in[8];
  const float* bcat = (const float*)d_in[9];
  float* out = (float*)d_out;
  float* ws  = (float*)d_ws;

  hipLaunchKernelGGL(decoder_persist, dim3(NBLK), dim3(NTHR), 0, stream,
                     enc, hid, cel, wih, whh, bih, bhh, wcat, bcat, out, ws);
}